// Round 8
// baseline (398.982 us; speedup 1.0000x reference)
//
#include <hip/hip_runtime.h>

#define C 128
#define KORD 6
#define KD (KORD * C)  // 768 fused reduction dim
#define EPB 4096       // edges per block in phase-1

typedef __attribute__((ext_vector_type(8))) short short8;   // 8 bf16
typedef __attribute__((ext_vector_type(4))) float f32x4;

// ---------- fp32 -> bf16 (RNE) ----------
__device__ __forceinline__ short f2bf(float f) {
  unsigned u = __float_as_uint(f);
  unsigned r = (u + 0x7fffu + ((u >> 16) & 1u)) >> 16;
  return (short)r;
}
__device__ __forceinline__ float bf2f(short s) {
  return __uint_as_float(((unsigned)(unsigned short)s) << 16);
}

// ---------- monotone float<->uint encoding for atomicMax over floats ----------
__device__ __forceinline__ unsigned enc_f32(float f) {
  unsigned u = __float_as_uint(f);
  return (u & 0x80000000u) ? ~u : (u | 0x80000000u);
}
__device__ __forceinline__ float dec_f32(unsigned u) {
  return (u & 0x80000000u) ? __uint_as_float(u ^ 0x80000000u) : __uint_as_float(~u);
}

// ---------- fused: Wt transpose + bsum ----------
__global__ void prep_kernel(const float* __restrict__ W, const float* __restrict__ bd,
                            const float* __restrict__ bias, short* __restrict__ Wt,
                            float* __restrict__ bsum) {
  int i = blockIdx.x * blockDim.x + threadIdx.x;
  if (i < KD * C) {
    int k = i >> 7, nn = i & 127;
    Wt[(size_t)nn * KD + k] = f2bf(W[i]);
  }
  if (i < C) {
    float s = bias[i];
#pragma unroll
    for (int k = 0; k < KORD; ++k) s += bd[k * C + i];
    bsum[i] = s;
  }
}

// ---------- nodes -> bf16 slot 0 of Xb (n x 768) ----------
__global__ void cvt_nodes_kernel(const float* __restrict__ nodes, short* __restrict__ xb, int n) {
  int idx = blockIdx.x * blockDim.x + threadIdx.x;  // n*32
  if (idx >= n * 32) return;
  int row = idx >> 5, c4 = idx & 31;
  float4 v = ((const float4*)nodes)[(size_t)row * 32 + c4];
  short4 o;
  o.x = f2bf(v.x); o.y = f2bf(v.y); o.z = f2bf(v.z); o.w = f2bf(v.w);
  ((short4*)(xb + (size_t)row * KD))[c4] = o;
}

// ---------- phase 1a: coarse bucket histogram (LDS atomics only) + max(-w) ----------
__global__ __launch_bounds__(256) void p1_count_kernel(const int* __restrict__ senders,
                                                       const float* __restrict__ edges, int ne,
                                                       int* __restrict__ hist, int NB,
                                                       unsigned* __restrict__ umax) {
  __shared__ int h[256];
  int t = threadIdx.x;
  h[t] = 0;
  __syncthreads();
  int base = blockIdx.x * EPB;
  int end = min(base + EPB, ne);
  float m = -INFINITY;
  for (int i = base + t; i < end; i += 256) {
    atomicAdd(&h[senders[i] >> 8], 1);
    m = fmaxf(m, -edges[i]);
  }
#pragma unroll
  for (int off = 32; off > 0; off >>= 1) m = fmaxf(m, __shfl_down(m, off, 64));
  if ((t & 63) == 0) atomicMax(umax, enc_f32(m));
  __syncthreads();
  hist[t * NB + blockIdx.x] = h[t];
}

// ---------- multiblock exclusive scan, stage 1 ----------
__global__ __launch_bounds__(1024) void scan1_kernel(const int* __restrict__ counts,
                                                     int* __restrict__ offsets,
                                                     int* __restrict__ bsums, int n) {
  int t = threadIdx.x;
  int i = blockIdx.x * 1024 + t;
  int lane = t & 63, w = t >> 6;
  int v = (i < n) ? counts[i] : 0;
  int s = v;
#pragma unroll
  for (int d = 1; d < 64; d <<= 1) {
    int o = __shfl_up(s, d, 64);
    if (lane >= d) s += o;
  }
  __shared__ int wsum[16];
  if (lane == 63) wsum[w] = s;
  __syncthreads();
  if (t < 16) {
    int ws = wsum[t];
#pragma unroll
    for (int d = 1; d < 16; d <<= 1) {
      int o = __shfl_up(ws, d, 64);
      if (t >= d) ws += o;
    }
    wsum[t] = ws;
  }
  __syncthreads();
  int excl = s - v + (w > 0 ? wsum[w - 1] : 0);
  if (i < n) offsets[i] = excl;
  if (t == 1023) bsums[blockIdx.x] = wsum[15];
}

// ---------- stage 2: scan of block sums (nb <= 1024) ----------
__global__ __launch_bounds__(1024) void scan2_kernel(int* __restrict__ bsums, int nb) {
  int t = threadIdx.x;
  int lane = t & 63, w = t >> 6;
  int v = (t < nb) ? bsums[t] : 0;
  int s = v;
#pragma unroll
  for (int d = 1; d < 64; d <<= 1) {
    int o = __shfl_up(s, d, 64);
    if (lane >= d) s += o;
  }
  __shared__ int wsum[16];
  if (lane == 63) wsum[w] = s;
  __syncthreads();
  if (t < 16) {
    int ws = wsum[t];
#pragma unroll
    for (int d = 1; d < 16; d <<= 1) {
      int o = __shfl_up(ws, d, 64);
      if (t >= d) ws += o;
    }
    wsum[t] = ws;
  }
  __syncthreads();
  int excl = s - v + (w > 0 ? wsum[w - 1] : 0);
  if (t < nb) bsums[t] = excl;
}

// ---------- phase 1b: scatter into coarse buckets; applies bsums (scan3 folded) ----------
__global__ __launch_bounds__(256) void p1_scatter_kernel(
    const int* __restrict__ senders, const int* __restrict__ receivers,
    const float* __restrict__ edges, int ne, const int* __restrict__ scanned,
    const int* __restrict__ bsums, int NB, int2* __restrict__ bkt) {
  __shared__ int basec[256];
  int t = threadIdx.x;
  int idx = t * NB + blockIdx.x;
  basec[t] = scanned[idx] + bsums[idx >> 10];
  __syncthreads();
  int base = blockIdx.x * EPB;
  int end = min(base + EPB, ne);
  for (int i = base + t; i < end; i += 256) {
    int s = senders[i];
    int pos = atomicAdd(&basec[s >> 8], 1);
    int2 rec;
    rec.x = __float_as_int(edges[i]);
    rec.y = receivers[i] | ((s & 255) << 16);
    bkt[pos] = rec;
  }
}

// ---------- phase 2: per-bucket CSR finalize + offsets + deg + deg-max (scan3 folded) ----------
__global__ __launch_bounds__(256) void p2_finalize_kernel(
    const int2* __restrict__ bkt, const int* __restrict__ scanned,
    const int* __restrict__ bsums, int NB, int NBUCK, int ne, int n, int2* __restrict__ csr_wr,
    int* __restrict__ offsets, float* __restrict__ degf, unsigned* __restrict__ umax) {
  __shared__ int h[256];
  __shared__ int cur[256];
  __shared__ float dg[256];
  __shared__ int wsum[4];
  __shared__ float wmax[4];
  int t = threadIdx.x;
  int b = blockIdx.x;
  int i0 = b * NB;
  int base = scanned[i0] + bsums[i0 >> 10];
  int bend = ne;
  if (b != NBUCK - 1) {
    int i1 = (b + 1) * NB;
    bend = scanned[i1] + bsums[i1 >> 10];
  }
  h[t] = 0;
  dg[t] = 0.f;
  __syncthreads();
  for (int i = base + t; i < bend; i += 256) atomicAdd(&h[(bkt[i].y >> 16) & 255], 1);
  __syncthreads();
  int lane = t & 63, w = t >> 6;
  int v = h[t];
  int s = v;
#pragma unroll
  for (int d = 1; d < 64; d <<= 1) {
    int o = __shfl_up(s, d, 64);
    if (lane >= d) s += o;
  }
  if (lane == 63) wsum[w] = s;
  __syncthreads();
  int carry = 0;
#pragma unroll
  for (int j = 0; j < 4; ++j) carry += (j < w) ? wsum[j] : 0;
  int excl = s - v + carry;
  int node = b * 256 + t;
  if (node < n) offsets[node] = base + excl;
  cur[t] = base + excl;
  __syncthreads();
  for (int i = base + t; i < bend; i += 256) {
    int2 rec = bkt[i];
    int bin = (rec.y >> 16) & 255;
    int pos = atomicAdd(&cur[bin], 1);
    int2 outrec;
    outrec.x = rec.x;
    outrec.y = rec.y & 0xFFFF;
    csr_wr[pos] = outrec;
    atomicAdd(&dg[bin], __int_as_float(rec.x));
  }
  __syncthreads();
  float d = dg[t];
  if (node < n) degf[node] = d;
  float m = (node < n) ? d : 0.f;
#pragma unroll
  for (int off = 32; off > 0; off >>= 1) m = fmaxf(m, __shfl_down(m, off, 64));
  if (lane == 0) wmax[w] = m;
  __syncthreads();
  if (t == 0) {
    float mm = fmaxf(fmaxf(wmax[0], wmax[1]), fmaxf(wmax[2], wmax[3]));
    atomicMax(umax, enc_f32(mm));
    if (b == NBUCK - 1) offsets[n] = ne;
  }
}

// ---------- scale = 2/lambda_max = 1/max ----------
__global__ void scale_kernel(const unsigned* __restrict__ umax, float* __restrict__ scalep) {
  *scalep = 1.0f / dec_f32(*umax);
}

// ---------- Tx_k = coef*scale*(deg*x - A x) - z, bf16 state in Xb slots ----------
// One wave per node; quarter-wave (16 lanes x short8 = 256 B row) per edge.
// Edge loop unrolled x4 with 4 independent accumulator sets -> 16 gathers in
// flight per wave (vs 4), attacking the load-latency bound seen in R7.
__global__ __launch_bounds__(256) void matvec_kernel(
    const short* __restrict__ xg,   // gather/diag source slot (row stride KD)
    const short* __restrict__ zg,   // z slot or nullptr
    short* __restrict__ yg,         // output slot
    const float* __restrict__ deg, const int* __restrict__ offsets,
    const int2* __restrict__ csr_wr, const float* __restrict__ scalep, float coef, int n) {
  int wid = (blockIdx.x * blockDim.x + threadIdx.x) >> 6;
  int lane = threadIdx.x & 63;
  int sub = lane & 15;
  int quarter = lane >> 4;
  if (wid >= n) return;
  float sc = scalep[0] * coef;
  int e0 = offsets[wid], e1 = offsets[wid + 1];
  float a0[8], a1[8], a2[8], a3[8];
#pragma unroll
  for (int j = 0; j < 8; ++j) { a0[j] = 0.f; a1[j] = 0.f; a2[j] = 0.f; a3[j] = 0.f; }
  int e = e0 + quarter;
  // main: 4 edges per quarter-wave per iteration, independent chains
  for (; e + 12 < e1; e += 16) {
    int2 p0 = csr_wr[e];
    int2 p1 = csr_wr[e + 4];
    int2 p2 = csr_wr[e + 8];
    int2 p3 = csr_wr[e + 12];
    short8 v0 = *(const short8*)(xg + (size_t)p0.y * KD + sub * 8);
    short8 v1 = *(const short8*)(xg + (size_t)p1.y * KD + sub * 8);
    short8 v2 = *(const short8*)(xg + (size_t)p2.y * KD + sub * 8);
    short8 v3 = *(const short8*)(xg + (size_t)p3.y * KD + sub * 8);
    float w0 = __int_as_float(p0.x), w1 = __int_as_float(p1.x);
    float w2 = __int_as_float(p2.x), w3 = __int_as_float(p3.x);
#pragma unroll
    for (int j = 0; j < 8; ++j) {
      a0[j] = fmaf(w0, bf2f(v0[j]), a0[j]);
      a1[j] = fmaf(w1, bf2f(v1[j]), a1[j]);
      a2[j] = fmaf(w2, bf2f(v2[j]), a2[j]);
      a3[j] = fmaf(w3, bf2f(v3[j]), a3[j]);
    }
  }
  // tail: one edge at a time
  for (; e < e1; e += 4) {
    int2 p = csr_wr[e];
    float w = __int_as_float(p.x);
    short8 v = *(const short8*)(xg + (size_t)p.y * KD + sub * 8);
#pragma unroll
    for (int j = 0; j < 8; ++j) a0[j] = fmaf(w, bf2f(v[j]), a0[j]);
  }
  float a[8];
#pragma unroll
  for (int j = 0; j < 8; ++j) {
    a[j] = (a0[j] + a1[j]) + (a2[j] + a3[j]);
    a[j] += __shfl_xor(a[j], 16, 64);
    a[j] += __shfl_xor(a[j], 32, 64);
  }
  if (quarter == 0) {
    float d = deg[wid];
    short8 xo = *(const short8*)(xg + (size_t)wid * KD + sub * 8);
    float r[8];
#pragma unroll
    for (int j = 0; j < 8; ++j) r[j] = sc * fmaf(d, bf2f(xo[j]), -a[j]);
    if (zg) {
      short8 zv = *(const short8*)(zg + (size_t)wid * KD + sub * 8);
#pragma unroll
      for (int j = 0; j < 8; ++j) r[j] -= bf2f(zv[j]);
    }
    short8 o;
#pragma unroll
    for (int j = 0; j < 8; ++j) o[j] = f2bf(r[j]);
    *(short8*)(yg + (size_t)wid * KD + sub * 8) = o;
  }
}

// ---------- fused GEMM: out = Xb (n x 768 bf16) @ W (768x128) + bsum ----------
#define BK 64
#define LDP (BK + 8)  // padded row stride in shorts
__global__ __launch_bounds__(256) void mfma_gemm_kernel(const short* __restrict__ Xb,
                                                        const short* __restrict__ Wt,
                                                        const float* __restrict__ bsum,
                                                        float* __restrict__ out, int n) {
  __shared__ short Al[64 * LDP];
  __shared__ short Bl[128 * LDP];
  int t = threadIdx.x;
  int w = t >> 6, lane = t & 63;
  int m = lane & 15, q = lane >> 4;
  int row0 = blockIdx.x * 64;
  int c0 = w * 32;

  f32x4 acc[4][2];
#pragma unroll
  for (int i = 0; i < 4; ++i)
#pragma unroll
    for (int j = 0; j < 2; ++j) acc[i][j] = (f32x4){0.f, 0.f, 0.f, 0.f};

  for (int k0 = 0; k0 < KD; k0 += BK) {
    __syncthreads();
#pragma unroll
    for (int p = 0; p < 2; ++p) {
      int idx = t + 256 * p;
      int r = idx >> 3, u = idx & 7;
      int gr = min(row0 + r, n - 1);
      short8 v = *(const short8*)(Xb + (size_t)gr * KD + k0 + u * 8);
      *(short8*)(Al + r * LDP + u * 8) = v;
    }
#pragma unroll
    for (int p = 0; p < 4; ++p) {
      int idx = t + 256 * p;
      int cc = idx >> 3, u = idx & 7;
      short8 v = *(const short8*)(Wt + (size_t)cc * KD + k0 + u * 8);
      *(short8*)(Bl + cc * LDP + u * 8) = v;
    }
    __syncthreads();
#pragma unroll
    for (int s = 0; s < 2; ++s) {
      int ko = s * 32 + q * 8;
      short8 b0 = *(const short8*)(Bl + (c0 + m) * LDP + ko);
      short8 b1 = *(const short8*)(Bl + (c0 + 16 + m) * LDP + ko);
#pragma unroll
      for (int rt = 0; rt < 4; ++rt) {
        short8 av = *(const short8*)(Al + (rt * 16 + m) * LDP + ko);
        acc[rt][0] = __builtin_amdgcn_mfma_f32_16x16x32_bf16(av, b0, acc[rt][0], 0, 0, 0);
        acc[rt][1] = __builtin_amdgcn_mfma_f32_16x16x32_bf16(av, b1, acc[rt][1], 0, 0, 0);
      }
    }
  }

#pragma unroll
  for (int ct = 0; ct < 2; ++ct) {
    int col = c0 + ct * 16 + m;
    float bs = bsum[col];
#pragma unroll
    for (int rt = 0; rt < 4; ++rt) {
#pragma unroll
      for (int i = 0; i < 4; ++i) {
        int row = row0 + rt * 16 + q * 4 + i;
        if (row < n) out[(size_t)row * C + col] = acc[rt][ct][i] + bs;
      }
    }
  }
}

extern "C" void kernel_launch(void* const* d_in, const int* in_sizes, int n_in,
                              void* d_out, int out_size, void* d_ws, size_t ws_size,
                              hipStream_t stream) {
  const float* nodes = (const float*)d_in[0];
  const float* edges = (const float*)d_in[1];
  const int* senders = (const int*)d_in[2];
  const int* receivers = (const int*)d_in[3];
  const float* W = (const float*)d_in[4];
  const float* b_dense = (const float*)d_in[5];
  const float* bias = (const float*)d_in[6];
  float* out = (float*)d_out;
  int n = in_sizes[0] / C;
  int ne = in_sizes[1];
  int NB = (ne + EPB - 1) / EPB;          // phase-1 blocks
  int NBUCK = (n + 255) >> 8;             // coarse buckets (sender>>8)
  int M = 256 * NB;                       // scan table length
  int nb2 = (M + 1023) / 1024;

  char* ws = (char*)d_ws;
  size_t off = 0;
  auto alloc = [&](size_t b) { size_t r = off; off += (b + 255) & ~(size_t)255; return r; };
  float* degf = (float*)(ws + alloc((size_t)n * 4));
  int* offsets = (int*)(ws + alloc((size_t)(n + 1) * 4));
  int* hist = (int*)(ws + alloc((size_t)M * 4));
  int* bsums = (int*)(ws + alloc((size_t)nb2 * 4));
  int2* bkt = (int2*)(ws + alloc((size_t)ne * 8));
  int2* csr_wr = (int2*)(ws + alloc((size_t)ne * 8));
  unsigned* umax = (unsigned*)(ws + alloc(4));
  float* scalep = (float*)(ws + alloc(4));
  float* bsum = (float*)(ws + alloc(C * 4));
  short* Xb = (short*)(ws + alloc((size_t)n * KD * 2));
  short* Wt = (short*)(ws + alloc((size_t)KD * C * 2));
  (void)ws_size; (void)n_in; (void)out_size;

  hipMemsetAsync(umax, 0, 4, stream);

  prep_kernel<<<(KD * C + 255) / 256, 256, 0, stream>>>(W, b_dense, bias, Wt, bsum);
  cvt_nodes_kernel<<<(n * 32 + 255) / 256, 256, 0, stream>>>(nodes, Xb, n);

  // CSR build — no global atomics (LDS atomics + scans only)
  p1_count_kernel<<<NB, 256, 0, stream>>>(senders, edges, ne, hist, NB, umax);
  scan1_kernel<<<nb2, 1024, 0, stream>>>(hist, hist, bsums, M);
  scan2_kernel<<<1, 1024, 0, stream>>>(bsums, nb2);
  p1_scatter_kernel<<<NB, 256, 0, stream>>>(senders, receivers, edges, ne, hist, bsums, NB, bkt);
  p2_finalize_kernel<<<NBUCK, 256, 0, stream>>>(bkt, hist, bsums, NB, NBUCK, ne, n, csr_wr,
                                                offsets, degf, umax);
  scale_kernel<<<1, 1, 0, stream>>>(umax, scalep);

  int mvblocks = (n * 64 + 255) / 256;

  // Chebyshev recurrence, all state bf16 in Xb slots:
  matvec_kernel<<<mvblocks, 256, 0, stream>>>(Xb + 0 * C, nullptr, Xb + 1 * C,
                                              degf, offsets, csr_wr, scalep, 1.0f, n);
  matvec_kernel<<<mvblocks, 256, 0, stream>>>(Xb + 1 * C, Xb + 0 * C, Xb + 2 * C,
                                              degf, offsets, csr_wr, scalep, 2.0f, n);
  matvec_kernel<<<mvblocks, 256, 0, stream>>>(Xb + 2 * C, Xb + 1 * C, Xb + 3 * C,
                                              degf, offsets, csr_wr, scalep, 2.0f, n);
  matvec_kernel<<<mvblocks, 256, 0, stream>>>(Xb + 3 * C, Xb + 2 * C, Xb + 4 * C,
                                              degf, offsets, csr_wr, scalep, 2.0f, n);
  matvec_kernel<<<mvblocks, 256, 0, stream>>>(Xb + 4 * C, Xb + 3 * C, Xb + 5 * C,
                                              degf, offsets, csr_wr, scalep, 2.0f, n);

  // out = Xb @ vstack(W) + (sum_k b_k + bias), LDS-staged MFMA GEMM
  mfma_gemm_kernel<<<(n + 63) / 64, 256, 0, stream>>>(Xb, Wt, bsum, out, n);
}

// Round 9
// 342.579 us; speedup vs baseline: 1.1646x; 1.1646x over previous
//
#include <hip/hip_runtime.h>

#define C 128
#define KORD 6
#define KD (KORD * C)  // 768 fused reduction dim
#define EPB 4096       // edges per block in phase-1

typedef __attribute__((ext_vector_type(8))) short short8;   // 8 bf16
typedef __attribute__((ext_vector_type(4))) float f32x4;

// ---------- fp32 -> bf16 (RNE) ----------
__device__ __forceinline__ short f2bf(float f) {
  unsigned u = __float_as_uint(f);
  unsigned r = (u + 0x7fffu + ((u >> 16) & 1u)) >> 16;
  return (short)r;
}
__device__ __forceinline__ float bf2f(short s) {
  return __uint_as_float(((unsigned)(unsigned short)s) << 16);
}

// ---------- monotone float<->uint encoding for atomicMax over floats ----------
__device__ __forceinline__ unsigned enc_f32(float f) {
  unsigned u = __float_as_uint(f);
  return (u & 0x80000000u) ? ~u : (u | 0x80000000u);
}
__device__ __forceinline__ float dec_f32(unsigned u) {
  return (u & 0x80000000u) ? __uint_as_float(u ^ 0x80000000u) : __uint_as_float(~u);
}

// ---------- fused: Wt transpose + bsum ----------
__global__ void prep_kernel(const float* __restrict__ W, const float* __restrict__ bd,
                            const float* __restrict__ bias, short* __restrict__ Wt,
                            float* __restrict__ bsum) {
  int i = blockIdx.x * blockDim.x + threadIdx.x;
  if (i < KD * C) {
    int k = i >> 7, nn = i & 127;
    Wt[(size_t)nn * KD + k] = f2bf(W[i]);
  }
  if (i < C) {
    float s = bias[i];
#pragma unroll
    for (int k = 0; k < KORD; ++k) s += bd[k * C + i];
    bsum[i] = s;
  }
}

// ---------- nodes -> bf16 slot 0 of Xb (n x 768) ----------
__global__ void cvt_nodes_kernel(const float* __restrict__ nodes, short* __restrict__ xb, int n) {
  int idx = blockIdx.x * blockDim.x + threadIdx.x;  // n*32
  if (idx >= n * 32) return;
  int row = idx >> 5, c4 = idx & 31;
  float4 v = ((const float4*)nodes)[(size_t)row * 32 + c4];
  short4 o;
  o.x = f2bf(v.x); o.y = f2bf(v.y); o.z = f2bf(v.z); o.w = f2bf(v.w);
  ((short4*)(xb + (size_t)row * KD))[c4] = o;
}

// ---------- phase 1a: coarse bucket histogram (LDS atomics only) + max(-w) ----------
__global__ __launch_bounds__(256) void p1_count_kernel(const int* __restrict__ senders,
                                                       const float* __restrict__ edges, int ne,
                                                       int* __restrict__ hist, int NB,
                                                       unsigned* __restrict__ umax) {
  __shared__ int h[256];
  int t = threadIdx.x;
  h[t] = 0;
  __syncthreads();
  int base = blockIdx.x * EPB;
  int end = min(base + EPB, ne);
  float m = -INFINITY;
  for (int i = base + t; i < end; i += 256) {
    atomicAdd(&h[senders[i] >> 8], 1);
    m = fmaxf(m, -edges[i]);
  }
#pragma unroll
  for (int off = 32; off > 0; off >>= 1) m = fmaxf(m, __shfl_down(m, off, 64));
  if ((t & 63) == 0) atomicMax(umax, enc_f32(m));
  __syncthreads();
  hist[t * NB + blockIdx.x] = h[t];
}

// ---------- multiblock exclusive scan, stage 1 ----------
__global__ __launch_bounds__(1024) void scan1_kernel(const int* __restrict__ counts,
                                                     int* __restrict__ offsets,
                                                     int* __restrict__ bsums, int n) {
  int t = threadIdx.x;
  int i = blockIdx.x * 1024 + t;
  int lane = t & 63, w = t >> 6;
  int v = (i < n) ? counts[i] : 0;
  int s = v;
#pragma unroll
  for (int d = 1; d < 64; d <<= 1) {
    int o = __shfl_up(s, d, 64);
    if (lane >= d) s += o;
  }
  __shared__ int wsum[16];
  if (lane == 63) wsum[w] = s;
  __syncthreads();
  if (t < 16) {
    int ws = wsum[t];
#pragma unroll
    for (int d = 1; d < 16; d <<= 1) {
      int o = __shfl_up(ws, d, 64);
      if (t >= d) ws += o;
    }
    wsum[t] = ws;
  }
  __syncthreads();
  int excl = s - v + (w > 0 ? wsum[w - 1] : 0);
  if (i < n) offsets[i] = excl;
  if (t == 1023) bsums[blockIdx.x] = wsum[15];
}

// ---------- stage 2: scan of block sums (nb <= 1024) ----------
__global__ __launch_bounds__(1024) void scan2_kernel(int* __restrict__ bsums, int nb) {
  int t = threadIdx.x;
  int lane = t & 63, w = t >> 6;
  int v = (t < nb) ? bsums[t] : 0;
  int s = v;
#pragma unroll
  for (int d = 1; d < 64; d <<= 1) {
    int o = __shfl_up(s, d, 64);
    if (lane >= d) s += o;
  }
  __shared__ int wsum[16];
  if (lane == 63) wsum[w] = s;
  __syncthreads();
  if (t < 16) {
    int ws = wsum[t];
#pragma unroll
    for (int d = 1; d < 16; d <<= 1) {
      int o = __shfl_up(ws, d, 64);
      if (t >= d) ws += o;
    }
    wsum[t] = ws;
  }
  __syncthreads();
  int excl = s - v + (w > 0 ? wsum[w - 1] : 0);
  if (t < nb) bsums[t] = excl;
}

// ---------- phase 1b: scatter into coarse buckets; applies bsums (scan3 folded) ----------
__global__ __launch_bounds__(256) void p1_scatter_kernel(
    const int* __restrict__ senders, const int* __restrict__ receivers,
    const float* __restrict__ edges, int ne, const int* __restrict__ scanned,
    const int* __restrict__ bsums, int NB, int2* __restrict__ bkt) {
  __shared__ int basec[256];
  int t = threadIdx.x;
  int idx = t * NB + blockIdx.x;
  basec[t] = scanned[idx] + bsums[idx >> 10];
  __syncthreads();
  int base = blockIdx.x * EPB;
  int end = min(base + EPB, ne);
  for (int i = base + t; i < end; i += 256) {
    int s = senders[i];
    int pos = atomicAdd(&basec[s >> 8], 1);
    int2 rec;
    rec.x = __float_as_int(edges[i]);
    rec.y = receivers[i] | ((s & 255) << 16);
    bkt[pos] = rec;
  }
}

// ---------- phase 2: per-bucket CSR finalize + offsets + deg + deg-max (scan3 folded) ----------
__global__ __launch_bounds__(256) void p2_finalize_kernel(
    const int2* __restrict__ bkt, const int* __restrict__ scanned,
    const int* __restrict__ bsums, int NB, int NBUCK, int ne, int n, int2* __restrict__ csr_wr,
    int* __restrict__ offsets, float* __restrict__ degf, unsigned* __restrict__ umax) {
  __shared__ int h[256];
  __shared__ int cur[256];
  __shared__ float dg[256];
  __shared__ int wsum[4];
  __shared__ float wmax[4];
  int t = threadIdx.x;
  int b = blockIdx.x;
  int i0 = b * NB;
  int base = scanned[i0] + bsums[i0 >> 10];
  int bend = ne;
  if (b != NBUCK - 1) {
    int i1 = (b + 1) * NB;
    bend = scanned[i1] + bsums[i1 >> 10];
  }
  h[t] = 0;
  dg[t] = 0.f;
  __syncthreads();
  for (int i = base + t; i < bend; i += 256) atomicAdd(&h[(bkt[i].y >> 16) & 255], 1);
  __syncthreads();
  int lane = t & 63, w = t >> 6;
  int v = h[t];
  int s = v;
#pragma unroll
  for (int d = 1; d < 64; d <<= 1) {
    int o = __shfl_up(s, d, 64);
    if (lane >= d) s += o;
  }
  if (lane == 63) wsum[w] = s;
  __syncthreads();
  int carry = 0;
#pragma unroll
  for (int j = 0; j < 4; ++j) carry += (j < w) ? wsum[j] : 0;
  int excl = s - v + carry;
  int node = b * 256 + t;
  if (node < n) offsets[node] = base + excl;
  cur[t] = base + excl;
  __syncthreads();
  for (int i = base + t; i < bend; i += 256) {
    int2 rec = bkt[i];
    int bin = (rec.y >> 16) & 255;
    int pos = atomicAdd(&cur[bin], 1);
    int2 outrec;
    outrec.x = rec.x;
    outrec.y = rec.y & 0xFFFF;
    csr_wr[pos] = outrec;
    atomicAdd(&dg[bin], __int_as_float(rec.x));
  }
  __syncthreads();
  float d = dg[t];
  if (node < n) degf[node] = d;
  float m = (node < n) ? d : 0.f;
#pragma unroll
  for (int off = 32; off > 0; off >>= 1) m = fmaxf(m, __shfl_down(m, off, 64));
  if (lane == 0) wmax[w] = m;
  __syncthreads();
  if (t == 0) {
    float mm = fmaxf(fmaxf(wmax[0], wmax[1]), fmaxf(wmax[2], wmax[3]));
    atomicMax(umax, enc_f32(mm));
    if (b == NBUCK - 1) offsets[n] = ne;
  }
}

// ---------- scale = 2/lambda_max = 1/max ----------
__global__ void scale_kernel(const unsigned* __restrict__ umax, float* __restrict__ scalep) {
  *scalep = 1.0f / dec_f32(*umax);
}

// ---------- Tx_k = coef*scale*(deg*x - A x) - z, bf16 state in Xb slots ----------
// One wave per node; quarter-wave (16 lanes x short8 = 256 B row) per edge.
// Predicated 2-edge batch per iteration: second edge's index clamped, weight
// zeroed when OOB -> always 2 independent gathers in flight per quarter
// (8/wave), engaged at the real degree (~16/node), single accumulator set
// (keeps VGPRs ~30 -- the R8 x4 unroll never engaged and cost occupancy).
__global__ __launch_bounds__(256) void matvec_kernel(
    const short* __restrict__ xg,   // gather/diag source slot (row stride KD)
    const short* __restrict__ zg,   // z slot or nullptr
    short* __restrict__ yg,         // output slot
    const float* __restrict__ deg, const int* __restrict__ offsets,
    const int2* __restrict__ csr_wr, const float* __restrict__ scalep, float coef, int n) {
  int wid = (blockIdx.x * blockDim.x + threadIdx.x) >> 6;
  int lane = threadIdx.x & 63;
  int sub = lane & 15;
  int quarter = lane >> 4;
  if (wid >= n) return;
  float sc = scalep[0] * coef;
  int e0 = offsets[wid], e1 = offsets[wid + 1];
  float a[8];
#pragma unroll
  for (int j = 0; j < 8; ++j) a[j] = 0.f;
  for (int e = e0 + quarter; e < e1; e += 8) {
    int eb = e + 4;
    int2 p0 = csr_wr[e];
    int2 p1 = csr_wr[min(eb, e1 - 1)];     // clamped: always in-bounds
    short8 v0 = *(const short8*)(xg + (size_t)p0.y * KD + sub * 8);
    short8 v1 = *(const short8*)(xg + (size_t)p1.y * KD + sub * 8);
    float w0 = __int_as_float(p0.x);
    float w1 = (eb < e1) ? __int_as_float(p1.x) : 0.f;  // predicate via weight
#pragma unroll
    for (int j = 0; j < 8; ++j) {
      a[j] = fmaf(w0, bf2f(v0[j]), a[j]);
      a[j] = fmaf(w1, bf2f(v1[j]), a[j]);
    }
  }
#pragma unroll
  for (int j = 0; j < 8; ++j) {
    a[j] += __shfl_xor(a[j], 16, 64);
    a[j] += __shfl_xor(a[j], 32, 64);
  }
  if (quarter == 0) {
    float d = deg[wid];
    short8 xo = *(const short8*)(xg + (size_t)wid * KD + sub * 8);
    float r[8];
#pragma unroll
    for (int j = 0; j < 8; ++j) r[j] = sc * fmaf(d, bf2f(xo[j]), -a[j]);
    if (zg) {
      short8 zv = *(const short8*)(zg + (size_t)wid * KD + sub * 8);
#pragma unroll
      for (int j = 0; j < 8; ++j) r[j] -= bf2f(zv[j]);
    }
    short8 o;
#pragma unroll
    for (int j = 0; j < 8; ++j) o[j] = f2bf(r[j]);
    *(short8*)(yg + (size_t)wid * KD + sub * 8) = o;
  }
}

// ---------- fused GEMM: out = Xb (n x 768 bf16) @ W (768x128) + bsum ----------
#define BK 64
#define LDP (BK + 8)  // padded row stride in shorts
__global__ __launch_bounds__(256) void mfma_gemm_kernel(const short* __restrict__ Xb,
                                                        const short* __restrict__ Wt,
                                                        const float* __restrict__ bsum,
                                                        float* __restrict__ out, int n) {
  __shared__ short Al[64 * LDP];
  __shared__ short Bl[128 * LDP];
  int t = threadIdx.x;
  int w = t >> 6, lane = t & 63;
  int m = lane & 15, q = lane >> 4;
  int row0 = blockIdx.x * 64;
  int c0 = w * 32;

  f32x4 acc[4][2];
#pragma unroll
  for (int i = 0; i < 4; ++i)
#pragma unroll
    for (int j = 0; j < 2; ++j) acc[i][j] = (f32x4){0.f, 0.f, 0.f, 0.f};

  for (int k0 = 0; k0 < KD; k0 += BK) {
    __syncthreads();
#pragma unroll
    for (int p = 0; p < 2; ++p) {
      int idx = t + 256 * p;
      int r = idx >> 3, u = idx & 7;
      int gr = min(row0 + r, n - 1);
      short8 v = *(const short8*)(Xb + (size_t)gr * KD + k0 + u * 8);
      *(short8*)(Al + r * LDP + u * 8) = v;
    }
#pragma unroll
    for (int p = 0; p < 4; ++p) {
      int idx = t + 256 * p;
      int cc = idx >> 3, u = idx & 7;
      short8 v = *(const short8*)(Wt + (size_t)cc * KD + k0 + u * 8);
      *(short8*)(Bl + cc * LDP + u * 8) = v;
    }
    __syncthreads();
#pragma unroll
    for (int s = 0; s < 2; ++s) {
      int ko = s * 32 + q * 8;
      short8 b0 = *(const short8*)(Bl + (c0 + m) * LDP + ko);
      short8 b1 = *(const short8*)(Bl + (c0 + 16 + m) * LDP + ko);
#pragma unroll
      for (int rt = 0; rt < 4; ++rt) {
        short8 av = *(const short8*)(Al + (rt * 16 + m) * LDP + ko);
        acc[rt][0] = __builtin_amdgcn_mfma_f32_16x16x32_bf16(av, b0, acc[rt][0], 0, 0, 0);
        acc[rt][1] = __builtin_amdgcn_mfma_f32_16x16x32_bf16(av, b1, acc[rt][1], 0, 0, 0);
      }
    }
  }

#pragma unroll
  for (int ct = 0; ct < 2; ++ct) {
    int col = c0 + ct * 16 + m;
    float bs = bsum[col];
#pragma unroll
    for (int rt = 0; rt < 4; ++rt) {
#pragma unroll
      for (int i = 0; i < 4; ++i) {
        int row = row0 + rt * 16 + q * 4 + i;
        if (row < n) out[(size_t)row * C + col] = acc[rt][ct][i] + bs;
      }
    }
  }
}

extern "C" void kernel_launch(void* const* d_in, const int* in_sizes, int n_in,
                              void* d_out, int out_size, void* d_ws, size_t ws_size,
                              hipStream_t stream) {
  const float* nodes = (const float*)d_in[0];
  const float* edges = (const float*)d_in[1];
  const int* senders = (const int*)d_in[2];
  const int* receivers = (const int*)d_in[3];
  const float* W = (const float*)d_in[4];
  const float* b_dense = (const float*)d_in[5];
  const float* bias = (const float*)d_in[6];
  float* out = (float*)d_out;
  int n = in_sizes[0] / C;
  int ne = in_sizes[1];
  int NB = (ne + EPB - 1) / EPB;          // phase-1 blocks
  int NBUCK = (n + 255) >> 8;             // coarse buckets (sender>>8)
  int M = 256 * NB;                       // scan table length
  int nb2 = (M + 1023) / 1024;

  char* ws = (char*)d_ws;
  size_t off = 0;
  auto alloc = [&](size_t b) { size_t r = off; off += (b + 255) & ~(size_t)255; return r; };
  float* degf = (float*)(ws + alloc((size_t)n * 4));
  int* offsets = (int*)(ws + alloc((size_t)(n + 1) * 4));
  int* hist = (int*)(ws + alloc((size_t)M * 4));
  int* bsums = (int*)(ws + alloc((size_t)nb2 * 4));
  int2* bkt = (int2*)(ws + alloc((size_t)ne * 8));
  int2* csr_wr = (int2*)(ws + alloc((size_t)ne * 8));
  unsigned* umax = (unsigned*)(ws + alloc(4));
  float* scalep = (float*)(ws + alloc(4));
  float* bsum = (float*)(ws + alloc(C * 4));
  short* Xb = (short*)(ws + alloc((size_t)n * KD * 2));
  short* Wt = (short*)(ws + alloc((size_t)KD * C * 2));
  (void)ws_size; (void)n_in; (void)out_size;

  hipMemsetAsync(umax, 0, 4, stream);

  prep_kernel<<<(KD * C + 255) / 256, 256, 0, stream>>>(W, b_dense, bias, Wt, bsum);
  cvt_nodes_kernel<<<(n * 32 + 255) / 256, 256, 0, stream>>>(nodes, Xb, n);

  // CSR build — no global atomics (LDS atomics + scans only)
  p1_count_kernel<<<NB, 256, 0, stream>>>(senders, edges, ne, hist, NB, umax);
  scan1_kernel<<<nb2, 1024, 0, stream>>>(hist, hist, bsums, M);
  scan2_kernel<<<1, 1024, 0, stream>>>(bsums, nb2);
  p1_scatter_kernel<<<NB, 256, 0, stream>>>(senders, receivers, edges, ne, hist, bsums, NB, bkt);
  p2_finalize_kernel<<<NBUCK, 256, 0, stream>>>(bkt, hist, bsums, NB, NBUCK, ne, n, csr_wr,
                                                offsets, degf, umax);
  scale_kernel<<<1, 1, 0, stream>>>(umax, scalep);

  int mvblocks = (n * 64 + 255) / 256;

  // Chebyshev recurrence, all state bf16 in Xb slots:
  matvec_kernel<<<mvblocks, 256, 0, stream>>>(Xb + 0 * C, nullptr, Xb + 1 * C,
                                              degf, offsets, csr_wr, scalep, 1.0f, n);
  matvec_kernel<<<mvblocks, 256, 0, stream>>>(Xb + 1 * C, Xb + 0 * C, Xb + 2 * C,
                                              degf, offsets, csr_wr, scalep, 2.0f, n);
  matvec_kernel<<<mvblocks, 256, 0, stream>>>(Xb + 2 * C, Xb + 1 * C, Xb + 3 * C,
                                              degf, offsets, csr_wr, scalep, 2.0f, n);
  matvec_kernel<<<mvblocks, 256, 0, stream>>>(Xb + 3 * C, Xb + 2 * C, Xb + 4 * C,
                                              degf, offsets, csr_wr, scalep, 2.0f, n);
  matvec_kernel<<<mvblocks, 256, 0, stream>>>(Xb + 4 * C, Xb + 3 * C, Xb + 5 * C,
                                              degf, offsets, csr_wr, scalep, 2.0f, n);

  // out = Xb @ vstack(W) + (sum_k b_k + bias), LDS-staged MFMA GEMM
  mfma_gemm_kernel<<<(n + 63) / 64, 256, 0, stream>>>(Xb, Wt, bsum, out, n);
}

// Round 10
// 335.421 us; speedup vs baseline: 1.1895x; 1.0213x over previous
//
#include <hip/hip_runtime.h>

#define C 128
#define KORD 6
#define KD (KORD * C)  // 768 fused reduction dim
#define EPB 4096       // edges per block in phase-1

typedef __attribute__((ext_vector_type(8))) short short8;   // 8 bf16
typedef __attribute__((ext_vector_type(4))) float f32x4;

// ---------- fp32 -> bf16 (RNE) ----------
__device__ __forceinline__ short f2bf(float f) {
  unsigned u = __float_as_uint(f);
  unsigned r = (u + 0x7fffu + ((u >> 16) & 1u)) >> 16;
  return (short)r;
}
__device__ __forceinline__ float bf2f(short s) {
  return __uint_as_float(((unsigned)(unsigned short)s) << 16);
}

// ---------- monotone float<->uint encoding for atomicMax over floats ----------
__device__ __forceinline__ unsigned enc_f32(float f) {
  unsigned u = __float_as_uint(f);
  return (u & 0x80000000u) ? ~u : (u | 0x80000000u);
}
__device__ __forceinline__ float dec_f32(unsigned u) {
  return (u & 0x80000000u) ? __uint_as_float(u ^ 0x80000000u) : __uint_as_float(~u);
}

// ---------- fused: Wt transpose + bsum ----------
__global__ void prep_kernel(const float* __restrict__ W, const float* __restrict__ bd,
                            const float* __restrict__ bias, short* __restrict__ Wt,
                            float* __restrict__ bsum) {
  int i = blockIdx.x * blockDim.x + threadIdx.x;
  if (i < KD * C) {
    int k = i >> 7, nn = i & 127;
    Wt[(size_t)nn * KD + k] = f2bf(W[i]);
  }
  if (i < C) {
    float s = bias[i];
#pragma unroll
    for (int k = 0; k < KORD; ++k) s += bd[k * C + i];
    bsum[i] = s;
  }
}

// ---------- nodes -> bf16 slot 0 of Xb (n x 768) ----------
__global__ void cvt_nodes_kernel(const float* __restrict__ nodes, short* __restrict__ xb, int n) {
  int idx = blockIdx.x * blockDim.x + threadIdx.x;  // n*32
  if (idx >= n * 32) return;
  int row = idx >> 5, c4 = idx & 31;
  float4 v = ((const float4*)nodes)[(size_t)row * 32 + c4];
  short4 o;
  o.x = f2bf(v.x); o.y = f2bf(v.y); o.z = f2bf(v.z); o.w = f2bf(v.w);
  ((short4*)(xb + (size_t)row * KD))[c4] = o;
}

// ---------- phase 1a: coarse bucket histogram (LDS atomics only) + max(-w) ----------
__global__ __launch_bounds__(256) void p1_count_kernel(const int* __restrict__ senders,
                                                       const float* __restrict__ edges, int ne,
                                                       int* __restrict__ hist, int NB,
                                                       unsigned* __restrict__ umax) {
  __shared__ int h[256];
  int t = threadIdx.x;
  h[t] = 0;
  __syncthreads();
  int base = blockIdx.x * EPB;
  int end = min(base + EPB, ne);
  float m = -INFINITY;
  for (int i = base + t; i < end; i += 256) {
    atomicAdd(&h[senders[i] >> 8], 1);
    m = fmaxf(m, -edges[i]);
  }
#pragma unroll
  for (int off = 32; off > 0; off >>= 1) m = fmaxf(m, __shfl_down(m, off, 64));
  if ((t & 63) == 0) atomicMax(umax, enc_f32(m));
  __syncthreads();
  hist[t * NB + blockIdx.x] = h[t];
}

// ---------- multiblock exclusive scan, stage 1 ----------
__global__ __launch_bounds__(1024) void scan1_kernel(const int* __restrict__ counts,
                                                     int* __restrict__ offsets,
                                                     int* __restrict__ bsums, int n) {
  int t = threadIdx.x;
  int i = blockIdx.x * 1024 + t;
  int lane = t & 63, w = t >> 6;
  int v = (i < n) ? counts[i] : 0;
  int s = v;
#pragma unroll
  for (int d = 1; d < 64; d <<= 1) {
    int o = __shfl_up(s, d, 64);
    if (lane >= d) s += o;
  }
  __shared__ int wsum[16];
  if (lane == 63) wsum[w] = s;
  __syncthreads();
  if (t < 16) {
    int ws = wsum[t];
#pragma unroll
    for (int d = 1; d < 16; d <<= 1) {
      int o = __shfl_up(ws, d, 64);
      if (t >= d) ws += o;
    }
    wsum[t] = ws;
  }
  __syncthreads();
  int excl = s - v + (w > 0 ? wsum[w - 1] : 0);
  if (i < n) offsets[i] = excl;
  if (t == 1023) bsums[blockIdx.x] = wsum[15];
}

// ---------- stage 2: scan of block sums (nb <= 1024) ----------
__global__ __launch_bounds__(1024) void scan2_kernel(int* __restrict__ bsums, int nb) {
  int t = threadIdx.x;
  int lane = t & 63, w = t >> 6;
  int v = (t < nb) ? bsums[t] : 0;
  int s = v;
#pragma unroll
  for (int d = 1; d < 64; d <<= 1) {
    int o = __shfl_up(s, d, 64);
    if (lane >= d) s += o;
  }
  __shared__ int wsum[16];
  if (lane == 63) wsum[w] = s;
  __syncthreads();
  if (t < 16) {
    int ws = wsum[t];
#pragma unroll
    for (int d = 1; d < 16; d <<= 1) {
      int o = __shfl_up(ws, d, 64);
      if (t >= d) ws += o;
    }
    wsum[t] = ws;
  }
  __syncthreads();
  int excl = s - v + (w > 0 ? wsum[w - 1] : 0);
  if (t < nb) bsums[t] = excl;
}

// ---------- phase 1b: scatter into coarse buckets; applies bsums (scan3 folded) ----------
__global__ __launch_bounds__(256) void p1_scatter_kernel(
    const int* __restrict__ senders, const int* __restrict__ receivers,
    const float* __restrict__ edges, int ne, const int* __restrict__ scanned,
    const int* __restrict__ bsums, int NB, int2* __restrict__ bkt) {
  __shared__ int basec[256];
  int t = threadIdx.x;
  int idx = t * NB + blockIdx.x;
  basec[t] = scanned[idx] + bsums[idx >> 10];
  __syncthreads();
  int base = blockIdx.x * EPB;
  int end = min(base + EPB, ne);
  for (int i = base + t; i < end; i += 256) {
    int s = senders[i];
    int pos = atomicAdd(&basec[s >> 8], 1);
    int2 rec;
    rec.x = __float_as_int(edges[i]);
    rec.y = receivers[i] | ((s & 255) << 16);
    bkt[pos] = rec;
  }
}

// ---------- phase 2: per-bucket CSR finalize + offsets + deg + deg-max (scan3 folded) ----------
__global__ __launch_bounds__(256) void p2_finalize_kernel(
    const int2* __restrict__ bkt, const int* __restrict__ scanned,
    const int* __restrict__ bsums, int NB, int NBUCK, int ne, int n, int2* __restrict__ csr_wr,
    int* __restrict__ offsets, float* __restrict__ degf, unsigned* __restrict__ umax) {
  __shared__ int h[256];
  __shared__ int cur[256];
  __shared__ float dg[256];
  __shared__ int wsum[4];
  __shared__ float wmax[4];
  int t = threadIdx.x;
  int b = blockIdx.x;
  int i0 = b * NB;
  int base = scanned[i0] + bsums[i0 >> 10];
  int bend = ne;
  if (b != NBUCK - 1) {
    int i1 = (b + 1) * NB;
    bend = scanned[i1] + bsums[i1 >> 10];
  }
  h[t] = 0;
  dg[t] = 0.f;
  __syncthreads();
  for (int i = base + t; i < bend; i += 256) atomicAdd(&h[(bkt[i].y >> 16) & 255], 1);
  __syncthreads();
  int lane = t & 63, w = t >> 6;
  int v = h[t];
  int s = v;
#pragma unroll
  for (int d = 1; d < 64; d <<= 1) {
    int o = __shfl_up(s, d, 64);
    if (lane >= d) s += o;
  }
  if (lane == 63) wsum[w] = s;
  __syncthreads();
  int carry = 0;
#pragma unroll
  for (int j = 0; j < 4; ++j) carry += (j < w) ? wsum[j] : 0;
  int excl = s - v + carry;
  int node = b * 256 + t;
  if (node < n) offsets[node] = base + excl;
  cur[t] = base + excl;
  __syncthreads();
  for (int i = base + t; i < bend; i += 256) {
    int2 rec = bkt[i];
    int bin = (rec.y >> 16) & 255;
    int pos = atomicAdd(&cur[bin], 1);
    int2 outrec;
    outrec.x = rec.x;
    outrec.y = rec.y & 0xFFFF;
    csr_wr[pos] = outrec;
    atomicAdd(&dg[bin], __int_as_float(rec.x));
  }
  __syncthreads();
  float d = dg[t];
  if (node < n) degf[node] = d;
  float m = (node < n) ? d : 0.f;
#pragma unroll
  for (int off = 32; off > 0; off >>= 1) m = fmaxf(m, __shfl_down(m, off, 64));
  if (lane == 0) wmax[w] = m;
  __syncthreads();
  if (t == 0) {
    float mm = fmaxf(fmaxf(wmax[0], wmax[1]), fmaxf(wmax[2], wmax[3]));
    atomicMax(umax, enc_f32(mm));
    if (b == NBUCK - 1) offsets[n] = ne;
  }
}

// ---------- scale = 2/lambda_max = 1/max ----------
__global__ void scale_kernel(const unsigned* __restrict__ umax, float* __restrict__ scalep) {
  *scalep = 1.0f / dec_f32(*umax);
}

// ---------- Tx_k = coef*scale*(deg*x - A x) - z, bf16 state in Xb slots ----------
// One wave per node; quarter-wave (16 lanes x short8 = 256 B row) per edge.
// Predicated 4-edge batch per iteration (indices clamped, weights zeroed when
// OOB) -> 4 independent gathers per quarter = 16/wave in flight, engaged at
// the real degree (~16/node). R9's 2-batch bought ~25%; this continues the
// measured MLP curve while keeping a single accumulator set (~50 VGPR, under
// the 64-VGPR waves/SIMD halving step).
__global__ __launch_bounds__(256) void matvec_kernel(
    const short* __restrict__ xg,   // gather/diag source slot (row stride KD)
    const short* __restrict__ zg,   // z slot or nullptr
    short* __restrict__ yg,         // output slot
    const float* __restrict__ deg, const int* __restrict__ offsets,
    const int2* __restrict__ csr_wr, const float* __restrict__ scalep, float coef, int n) {
  int wid = (blockIdx.x * blockDim.x + threadIdx.x) >> 6;
  int lane = threadIdx.x & 63;
  int sub = lane & 15;
  int quarter = lane >> 4;
  if (wid >= n) return;
  float sc = scalep[0] * coef;
  int e0 = offsets[wid], e1 = offsets[wid + 1];
  float a[8];
#pragma unroll
  for (int j = 0; j < 8; ++j) a[j] = 0.f;
  int elast = e1 - 1;
  for (int e = e0 + quarter; e < e1; e += 16) {
    int eb1 = e + 4, eb2 = e + 8, eb3 = e + 12;
    int2 p0 = csr_wr[e];
    int2 p1 = csr_wr[min(eb1, elast)];
    int2 p2 = csr_wr[min(eb2, elast)];
    int2 p3 = csr_wr[min(eb3, elast)];
    short8 v0 = *(const short8*)(xg + (size_t)p0.y * KD + sub * 8);
    short8 v1 = *(const short8*)(xg + (size_t)p1.y * KD + sub * 8);
    short8 v2 = *(const short8*)(xg + (size_t)p2.y * KD + sub * 8);
    short8 v3 = *(const short8*)(xg + (size_t)p3.y * KD + sub * 8);
    float w0 = __int_as_float(p0.x);
    float w1 = (eb1 < e1) ? __int_as_float(p1.x) : 0.f;
    float w2 = (eb2 < e1) ? __int_as_float(p2.x) : 0.f;
    float w3 = (eb3 < e1) ? __int_as_float(p3.x) : 0.f;
#pragma unroll
    for (int j = 0; j < 8; ++j) {
      float t0 = fmaf(w0, bf2f(v0[j]), a[j]);
      float t1 = fmaf(w1, bf2f(v1[j]), t0);
      float t2 = fmaf(w2, bf2f(v2[j]), t1);
      a[j] = fmaf(w3, bf2f(v3[j]), t2);
    }
  }
#pragma unroll
  for (int j = 0; j < 8; ++j) {
    a[j] += __shfl_xor(a[j], 16, 64);
    a[j] += __shfl_xor(a[j], 32, 64);
  }
  if (quarter == 0) {
    float d = deg[wid];
    short8 xo = *(const short8*)(xg + (size_t)wid * KD + sub * 8);
    float r[8];
#pragma unroll
    for (int j = 0; j < 8; ++j) r[j] = sc * fmaf(d, bf2f(xo[j]), -a[j]);
    if (zg) {
      short8 zv = *(const short8*)(zg + (size_t)wid * KD + sub * 8);
#pragma unroll
      for (int j = 0; j < 8; ++j) r[j] -= bf2f(zv[j]);
    }
    short8 o;
#pragma unroll
    for (int j = 0; j < 8; ++j) o[j] = f2bf(r[j]);
    *(short8*)(yg + (size_t)wid * KD + sub * 8) = o;
  }
}

// ---------- fused GEMM: out = Xb (n x 768 bf16) @ W (768x128) + bsum ----------
#define BK 64
#define LDP (BK + 8)  // padded row stride in shorts
__global__ __launch_bounds__(256) void mfma_gemm_kernel(const short* __restrict__ Xb,
                                                        const short* __restrict__ Wt,
                                                        const float* __restrict__ bsum,
                                                        float* __restrict__ out, int n) {
  __shared__ short Al[64 * LDP];
  __shared__ short Bl[128 * LDP];
  int t = threadIdx.x;
  int w = t >> 6, lane = t & 63;
  int m = lane & 15, q = lane >> 4;
  int row0 = blockIdx.x * 64;
  int c0 = w * 32;

  f32x4 acc[4][2];
#pragma unroll
  for (int i = 0; i < 4; ++i)
#pragma unroll
    for (int j = 0; j < 2; ++j) acc[i][j] = (f32x4){0.f, 0.f, 0.f, 0.f};

  for (int k0 = 0; k0 < KD; k0 += BK) {
    __syncthreads();
#pragma unroll
    for (int p = 0; p < 2; ++p) {
      int idx = t + 256 * p;
      int r = idx >> 3, u = idx & 7;
      int gr = min(row0 + r, n - 1);
      short8 v = *(const short8*)(Xb + (size_t)gr * KD + k0 + u * 8);
      *(short8*)(Al + r * LDP + u * 8) = v;
    }
#pragma unroll
    for (int p = 0; p < 4; ++p) {
      int idx = t + 256 * p;
      int cc = idx >> 3, u = idx & 7;
      short8 v = *(const short8*)(Wt + (size_t)cc * KD + k0 + u * 8);
      *(short8*)(Bl + cc * LDP + u * 8) = v;
    }
    __syncthreads();
#pragma unroll
    for (int s = 0; s < 2; ++s) {
      int ko = s * 32 + q * 8;
      short8 b0 = *(const short8*)(Bl + (c0 + m) * LDP + ko);
      short8 b1 = *(const short8*)(Bl + (c0 + 16 + m) * LDP + ko);
#pragma unroll
      for (int rt = 0; rt < 4; ++rt) {
        short8 av = *(const short8*)(Al + (rt * 16 + m) * LDP + ko);
        acc[rt][0] = __builtin_amdgcn_mfma_f32_16x16x32_bf16(av, b0, acc[rt][0], 0, 0, 0);
        acc[rt][1] = __builtin_amdgcn_mfma_f32_16x16x32_bf16(av, b1, acc[rt][1], 0, 0, 0);
      }
    }
  }

#pragma unroll
  for (int ct = 0; ct < 2; ++ct) {
    int col = c0 + ct * 16 + m;
    float bs = bsum[col];
#pragma unroll
    for (int rt = 0; rt < 4; ++rt) {
#pragma unroll
      for (int i = 0; i < 4; ++i) {
        int row = row0 + rt * 16 + q * 4 + i;
        if (row < n) out[(size_t)row * C + col] = acc[rt][ct][i] + bs;
      }
    }
  }
}

extern "C" void kernel_launch(void* const* d_in, const int* in_sizes, int n_in,
                              void* d_out, int out_size, void* d_ws, size_t ws_size,
                              hipStream_t stream) {
  const float* nodes = (const float*)d_in[0];
  const float* edges = (const float*)d_in[1];
  const int* senders = (const int*)d_in[2];
  const int* receivers = (const int*)d_in[3];
  const float* W = (const float*)d_in[4];
  const float* b_dense = (const float*)d_in[5];
  const float* bias = (const float*)d_in[6];
  float* out = (float*)d_out;
  int n = in_sizes[0] / C;
  int ne = in_sizes[1];
  int NB = (ne + EPB - 1) / EPB;          // phase-1 blocks
  int NBUCK = (n + 255) >> 8;             // coarse buckets (sender>>8)
  int M = 256 * NB;                       // scan table length
  int nb2 = (M + 1023) / 1024;

  char* ws = (char*)d_ws;
  size_t off = 0;
  auto alloc = [&](size_t b) { size_t r = off; off += (b + 255) & ~(size_t)255; return r; };
  float* degf = (float*)(ws + alloc((size_t)n * 4));
  int* offsets = (int*)(ws + alloc((size_t)(n + 1) * 4));
  int* hist = (int*)(ws + alloc((size_t)M * 4));
  int* bsums = (int*)(ws + alloc((size_t)nb2 * 4));
  int2* bkt = (int2*)(ws + alloc((size_t)ne * 8));
  int2* csr_wr = (int2*)(ws + alloc((size_t)ne * 8));
  unsigned* umax = (unsigned*)(ws + alloc(4));
  float* scalep = (float*)(ws + alloc(4));
  float* bsum = (float*)(ws + alloc(C * 4));
  short* Xb = (short*)(ws + alloc((size_t)n * KD * 2));
  short* Wt = (short*)(ws + alloc((size_t)KD * C * 2));
  (void)ws_size; (void)n_in; (void)out_size;

  hipMemsetAsync(umax, 0, 4, stream);

  prep_kernel<<<(KD * C + 255) / 256, 256, 0, stream>>>(W, b_dense, bias, Wt, bsum);
  cvt_nodes_kernel<<<(n * 32 + 255) / 256, 256, 0, stream>>>(nodes, Xb, n);

  // CSR build — no global atomics (LDS atomics + scans only)
  p1_count_kernel<<<NB, 256, 0, stream>>>(senders, edges, ne, hist, NB, umax);
  scan1_kernel<<<nb2, 1024, 0, stream>>>(hist, hist, bsums, M);
  scan2_kernel<<<1, 1024, 0, stream>>>(bsums, nb2);
  p1_scatter_kernel<<<NB, 256, 0, stream>>>(senders, receivers, edges, ne, hist, bsums, NB, bkt);
  p2_finalize_kernel<<<NBUCK, 256, 0, stream>>>(bkt, hist, bsums, NB, NBUCK, ne, n, csr_wr,
                                                offsets, degf, umax);
  scale_kernel<<<1, 1, 0, stream>>>(umax, scalep);

  int mvblocks = (n * 64 + 255) / 256;

  // Chebyshev recurrence, all state bf16 in Xb slots:
  matvec_kernel<<<mvblocks, 256, 0, stream>>>(Xb + 0 * C, nullptr, Xb + 1 * C,
                                              degf, offsets, csr_wr, scalep, 1.0f, n);
  matvec_kernel<<<mvblocks, 256, 0, stream>>>(Xb + 1 * C, Xb + 0 * C, Xb + 2 * C,
                                              degf, offsets, csr_wr, scalep, 2.0f, n);
  matvec_kernel<<<mvblocks, 256, 0, stream>>>(Xb + 2 * C, Xb + 1 * C, Xb + 3 * C,
                                              degf, offsets, csr_wr, scalep, 2.0f, n);
  matvec_kernel<<<mvblocks, 256, 0, stream>>>(Xb + 3 * C, Xb + 2 * C, Xb + 4 * C,
                                              degf, offsets, csr_wr, scalep, 2.0f, n);
  matvec_kernel<<<mvblocks, 256, 0, stream>>>(Xb + 4 * C, Xb + 3 * C, Xb + 5 * C,
                                              degf, offsets, csr_wr, scalep, 2.0f, n);

  // out = Xb @ vstack(W) + (sum_k b_k + bias), LDS-staged MFMA GEMM
  mfma_gemm_kernel<<<(n + 63) / 64, 256, 0, stream>>>(Xb, Wt, bsum, out, n);
}

// Round 11
// 325.881 us; speedup vs baseline: 1.2243x; 1.0293x over previous
//
#include <hip/hip_runtime.h>

#define C 128
#define KORD 6
#define KD (KORD * C)  // 768 fused reduction dim
#define EPB 4096       // edges per block in phase-1

typedef __attribute__((ext_vector_type(8))) short short8;   // 8 bf16
typedef __attribute__((ext_vector_type(4))) float f32x4;

// ---------- fp32 -> bf16 (RNE) ----------
__device__ __forceinline__ short f2bf(float f) {
  unsigned u = __float_as_uint(f);
  unsigned r = (u + 0x7fffu + ((u >> 16) & 1u)) >> 16;
  return (short)r;
}
__device__ __forceinline__ float bf2f(short s) {
  return __uint_as_float(((unsigned)(unsigned short)s) << 16);
}

// ---------- monotone float<->uint encoding for atomicMax over floats ----------
__device__ __forceinline__ unsigned enc_f32(float f) {
  unsigned u = __float_as_uint(f);
  return (u & 0x80000000u) ? ~u : (u | 0x80000000u);
}
__device__ __forceinline__ float dec_f32(unsigned u) {
  return (u & 0x80000000u) ? __uint_as_float(u ^ 0x80000000u) : __uint_as_float(~u);
}

// ---------- fused: Wt transpose + bsum + nodes->bf16 slot0 (one launch) ----------
__global__ void prep_kernel(const float* __restrict__ W, const float* __restrict__ bd,
                            const float* __restrict__ bias, short* __restrict__ Wt,
                            float* __restrict__ bsum, const float* __restrict__ nodes,
                            short* __restrict__ xb, int n) {
  int i = blockIdx.x * blockDim.x + threadIdx.x;
  if (i < KD * C) {
    int k = i >> 7, nn = i & 127;
    Wt[(size_t)nn * KD + k] = f2bf(W[i]);
  }
  if (i < C) {
    float s = bias[i];
#pragma unroll
    for (int k = 0; k < KORD; ++k) s += bd[k * C + i];
    bsum[i] = s;
  }
  if (i < n * 32) {
    int row = i >> 5, c4 = i & 31;
    float4 v = ((const float4*)nodes)[(size_t)row * 32 + c4];
    short4 o;
    o.x = f2bf(v.x); o.y = f2bf(v.y); o.z = f2bf(v.z); o.w = f2bf(v.w);
    ((short4*)(xb + (size_t)row * KD))[c4] = o;
  }
}

// ---------- phase 1a: coarse bucket histogram (LDS atomics only) + max(-w) ----------
__global__ __launch_bounds__(256) void p1_count_kernel(const int* __restrict__ senders,
                                                       const float* __restrict__ edges, int ne,
                                                       int* __restrict__ hist, int NB,
                                                       unsigned* __restrict__ umax) {
  __shared__ int h[256];
  int t = threadIdx.x;
  h[t] = 0;
  __syncthreads();
  int base = blockIdx.x * EPB;
  int end = min(base + EPB, ne);
  float m = -INFINITY;
  for (int i = base + t; i < end; i += 256) {
    atomicAdd(&h[senders[i] >> 8], 1);
    m = fmaxf(m, -edges[i]);
  }
#pragma unroll
  for (int off = 32; off > 0; off >>= 1) m = fmaxf(m, __shfl_down(m, off, 64));
  if ((t & 63) == 0) atomicMax(umax, enc_f32(m));
  __syncthreads();
  hist[t * NB + blockIdx.x] = h[t];
}

// ---------- multiblock exclusive scan, stage 1 ----------
__global__ __launch_bounds__(1024) void scan1_kernel(const int* __restrict__ counts,
                                                     int* __restrict__ offsets,
                                                     int* __restrict__ bsums, int n) {
  int t = threadIdx.x;
  int i = blockIdx.x * 1024 + t;
  int lane = t & 63, w = t >> 6;
  int v = (i < n) ? counts[i] : 0;
  int s = v;
#pragma unroll
  for (int d = 1; d < 64; d <<= 1) {
    int o = __shfl_up(s, d, 64);
    if (lane >= d) s += o;
  }
  __shared__ int wsum[16];
  if (lane == 63) wsum[w] = s;
  __syncthreads();
  if (t < 16) {
    int ws = wsum[t];
#pragma unroll
    for (int d = 1; d < 16; d <<= 1) {
      int o = __shfl_up(ws, d, 64);
      if (t >= d) ws += o;
    }
    wsum[t] = ws;
  }
  __syncthreads();
  int excl = s - v + (w > 0 ? wsum[w - 1] : 0);
  if (i < n) offsets[i] = excl;
  if (t == 1023) bsums[blockIdx.x] = wsum[15];
}

// ---------- stage 2: scan of block sums (nb <= 1024) ----------
__global__ __launch_bounds__(1024) void scan2_kernel(int* __restrict__ bsums, int nb) {
  int t = threadIdx.x;
  int lane = t & 63, w = t >> 6;
  int v = (t < nb) ? bsums[t] : 0;
  int s = v;
#pragma unroll
  for (int d = 1; d < 64; d <<= 1) {
    int o = __shfl_up(s, d, 64);
    if (lane >= d) s += o;
  }
  __shared__ int wsum[16];
  if (lane == 63) wsum[w] = s;
  __syncthreads();
  if (t < 16) {
    int ws = wsum[t];
#pragma unroll
    for (int d = 1; d < 16; d <<= 1) {
      int o = __shfl_up(ws, d, 64);
      if (t >= d) ws += o;
    }
    wsum[t] = ws;
  }
  __syncthreads();
  int excl = s - v + (w > 0 ? wsum[w - 1] : 0);
  if (t < nb) bsums[t] = excl;
}

// ---------- phase 1b: scatter into coarse buckets; applies bsums (scan3 folded) ----------
__global__ __launch_bounds__(256) void p1_scatter_kernel(
    const int* __restrict__ senders, const int* __restrict__ receivers,
    const float* __restrict__ edges, int ne, const int* __restrict__ scanned,
    const int* __restrict__ bsums, int NB, int2* __restrict__ bkt) {
  __shared__ int basec[256];
  int t = threadIdx.x;
  int idx = t * NB + blockIdx.x;
  basec[t] = scanned[idx] + bsums[idx >> 10];
  __syncthreads();
  int base = blockIdx.x * EPB;
  int end = min(base + EPB, ne);
  for (int i = base + t; i < end; i += 256) {
    int s = senders[i];
    int pos = atomicAdd(&basec[s >> 8], 1);
    int2 rec;
    rec.x = __float_as_int(edges[i]);
    rec.y = receivers[i] | ((s & 255) << 16);
    bkt[pos] = rec;
  }
}

// ---------- phase 2: CSR finalize + offsets + deg + deg-max + (last block) scale ----------
__global__ __launch_bounds__(256) void p2_finalize_kernel(
    const int2* __restrict__ bkt, const int* __restrict__ scanned,
    const int* __restrict__ bsums, int NB, int NBUCK, int ne, int n, int2* __restrict__ csr_wr,
    int* __restrict__ offsets, float* __restrict__ degf, unsigned* __restrict__ umax,
    int* __restrict__ ticket, float* __restrict__ scalep) {
  __shared__ int h[256];
  __shared__ int cur[256];
  __shared__ float dg[256];
  __shared__ int wsum[4];
  __shared__ float wmax[4];
  int t = threadIdx.x;
  int b = blockIdx.x;
  int i0 = b * NB;
  int base = scanned[i0] + bsums[i0 >> 10];
  int bend = ne;
  if (b != NBUCK - 1) {
    int i1 = (b + 1) * NB;
    bend = scanned[i1] + bsums[i1 >> 10];
  }
  h[t] = 0;
  dg[t] = 0.f;
  __syncthreads();
  for (int i = base + t; i < bend; i += 256) atomicAdd(&h[(bkt[i].y >> 16) & 255], 1);
  __syncthreads();
  int lane = t & 63, w = t >> 6;
  int v = h[t];
  int s = v;
#pragma unroll
  for (int d = 1; d < 64; d <<= 1) {
    int o = __shfl_up(s, d, 64);
    if (lane >= d) s += o;
  }
  if (lane == 63) wsum[w] = s;
  __syncthreads();
  int carry = 0;
#pragma unroll
  for (int j = 0; j < 4; ++j) carry += (j < w) ? wsum[j] : 0;
  int excl = s - v + carry;
  int node = b * 256 + t;
  if (node < n) offsets[node] = base + excl;
  cur[t] = base + excl;
  __syncthreads();
  for (int i = base + t; i < bend; i += 256) {
    int2 rec = bkt[i];
    int bin = (rec.y >> 16) & 255;
    int pos = atomicAdd(&cur[bin], 1);
    int2 outrec;
    outrec.x = rec.x;
    outrec.y = rec.y & 0xFFFF;
    csr_wr[pos] = outrec;
    atomicAdd(&dg[bin], __int_as_float(rec.x));
  }
  __syncthreads();
  float d = dg[t];
  if (node < n) degf[node] = d;
  float m = (node < n) ? d : 0.f;
#pragma unroll
  for (int off = 32; off > 0; off >>= 1) m = fmaxf(m, __shfl_down(m, off, 64));
  if (lane == 0) wmax[w] = m;
  __syncthreads();
  if (t == 0) {
    float mm = fmaxf(fmaxf(wmax[0], wmax[1]), fmaxf(wmax[2], wmax[3]));
    atomicMax(umax, enc_f32(mm));
    if (b == NBUCK - 1) offsets[n] = ne;
    __threadfence();  // publish umax before taking a ticket
    int done = atomicAdd(ticket, 1);
    if (done == NBUCK - 1) {
      // last finishing block: all atomicMax committed; read via RMW for atomicity
      unsigned cu = atomicMax(umax, 0u);
      scalep[0] = 1.0f / dec_f32(cu);
    }
  }
}

// ---------- Tx_k = coef*scale*(deg*x - A x) - z, bf16 state in Xb slots ----------
// One wave per node; quarter-wave (16 lanes x short8 = 256 B row) per edge.
// Predicated 4-edge batch (engages at real degree ~16). launch_bounds(256,8)
// caps VGPR at 64 to allow 8 blocks/CU: the kernel is latency-bound on random
// L3-served gathers, so resident-wave count is the lever (R10 showed per-wave
// MLP is exhausted). diag/z loads hoisted (exec-masked) to overlap the gather.
__global__ __launch_bounds__(256, 8) void matvec_kernel(
    const short* __restrict__ xg,   // gather/diag source slot (row stride KD)
    const short* __restrict__ zg,   // z slot or nullptr
    short* __restrict__ yg,         // output slot
    const float* __restrict__ deg, const int* __restrict__ offsets,
    const int2* __restrict__ csr_wr, const float* __restrict__ scalep, float coef, int n) {
  int wid = (blockIdx.x * blockDim.x + threadIdx.x) >> 6;
  int lane = threadIdx.x & 63;
  int sub = lane & 15;
  int quarter = lane >> 4;
  if (wid >= n) return;
  float sc = scalep[0] * coef;
  int e0 = offsets[wid], e1 = offsets[wid + 1];
  // hoisted epilogue operands (quarter 0 only; exec-masked loads overlap gathers)
  float d = 0.f;
  short8 xo, zv;
  if (quarter == 0) {
    d = deg[wid];
    xo = *(const short8*)(xg + (size_t)wid * KD + sub * 8);
    if (zg) zv = *(const short8*)(zg + (size_t)wid * KD + sub * 8);
  }
  float a[8];
#pragma unroll
  for (int j = 0; j < 8; ++j) a[j] = 0.f;
  int elast = e1 - 1;
  for (int e = e0 + quarter; e < e1; e += 16) {
    int eb1 = e + 4, eb2 = e + 8, eb3 = e + 12;
    int2 p0 = csr_wr[e];
    int2 p1 = csr_wr[min(eb1, elast)];
    int2 p2 = csr_wr[min(eb2, elast)];
    int2 p3 = csr_wr[min(eb3, elast)];
    short8 v0 = *(const short8*)(xg + (size_t)p0.y * KD + sub * 8);
    short8 v1 = *(const short8*)(xg + (size_t)p1.y * KD + sub * 8);
    short8 v2 = *(const short8*)(xg + (size_t)p2.y * KD + sub * 8);
    short8 v3 = *(const short8*)(xg + (size_t)p3.y * KD + sub * 8);
    float w0 = __int_as_float(p0.x);
    float w1 = (eb1 < e1) ? __int_as_float(p1.x) : 0.f;
    float w2 = (eb2 < e1) ? __int_as_float(p2.x) : 0.f;
    float w3 = (eb3 < e1) ? __int_as_float(p3.x) : 0.f;
#pragma unroll
    for (int j = 0; j < 8; ++j) {
      float t0 = fmaf(w0, bf2f(v0[j]), a[j]);
      float t1 = fmaf(w1, bf2f(v1[j]), t0);
      float t2 = fmaf(w2, bf2f(v2[j]), t1);
      a[j] = fmaf(w3, bf2f(v3[j]), t2);
    }
  }
#pragma unroll
  for (int j = 0; j < 8; ++j) {
    a[j] += __shfl_xor(a[j], 16, 64);
    a[j] += __shfl_xor(a[j], 32, 64);
  }
  if (quarter == 0) {
    float r[8];
#pragma unroll
    for (int j = 0; j < 8; ++j) r[j] = sc * fmaf(d, bf2f(xo[j]), -a[j]);
    if (zg) {
#pragma unroll
      for (int j = 0; j < 8; ++j) r[j] -= bf2f(zv[j]);
    }
    short8 o;
#pragma unroll
    for (int j = 0; j < 8; ++j) o[j] = f2bf(r[j]);
    *(short8*)(yg + (size_t)wid * KD + sub * 8) = o;
  }
}

// ---------- fused GEMM: out = Xb (n x 768 bf16) @ W (768x128) + bsum ----------
#define BK 64
#define LDP (BK + 8)  // padded row stride in shorts
__global__ __launch_bounds__(256) void mfma_gemm_kernel(const short* __restrict__ Xb,
                                                        const short* __restrict__ Wt,
                                                        const float* __restrict__ bsum,
                                                        float* __restrict__ out, int n) {
  __shared__ short Al[64 * LDP];
  __shared__ short Bl[128 * LDP];
  int t = threadIdx.x;
  int w = t >> 6, lane = t & 63;
  int m = lane & 15, q = lane >> 4;
  int row0 = blockIdx.x * 64;
  int c0 = w * 32;

  f32x4 acc[4][2];
#pragma unroll
  for (int i = 0; i < 4; ++i)
#pragma unroll
    for (int j = 0; j < 2; ++j) acc[i][j] = (f32x4){0.f, 0.f, 0.f, 0.f};

  for (int k0 = 0; k0 < KD; k0 += BK) {
    __syncthreads();
#pragma unroll
    for (int p = 0; p < 2; ++p) {
      int idx = t + 256 * p;
      int r = idx >> 3, u = idx & 7;
      int gr = min(row0 + r, n - 1);
      short8 v = *(const short8*)(Xb + (size_t)gr * KD + k0 + u * 8);
      *(short8*)(Al + r * LDP + u * 8) = v;
    }
#pragma unroll
    for (int p = 0; p < 4; ++p) {
      int idx = t + 256 * p;
      int cc = idx >> 3, u = idx & 7;
      short8 v = *(const short8*)(Wt + (size_t)cc * KD + k0 + u * 8);
      *(short8*)(Bl + cc * LDP + u * 8) = v;
    }
    __syncthreads();
#pragma unroll
    for (int s = 0; s < 2; ++s) {
      int ko = s * 32 + q * 8;
      short8 b0 = *(const short8*)(Bl + (c0 + m) * LDP + ko);
      short8 b1 = *(const short8*)(Bl + (c0 + 16 + m) * LDP + ko);
#pragma unroll
      for (int rt = 0; rt < 4; ++rt) {
        short8 av = *(const short8*)(Al + (rt * 16 + m) * LDP + ko);
        acc[rt][0] = __builtin_amdgcn_mfma_f32_16x16x32_bf16(av, b0, acc[rt][0], 0, 0, 0);
        acc[rt][1] = __builtin_amdgcn_mfma_f32_16x16x32_bf16(av, b1, acc[rt][1], 0, 0, 0);
      }
    }
  }

#pragma unroll
  for (int ct = 0; ct < 2; ++ct) {
    int col = c0 + ct * 16 + m;
    float bs = bsum[col];
#pragma unroll
    for (int rt = 0; rt < 4; ++rt) {
#pragma unroll
      for (int i = 0; i < 4; ++i) {
        int row = row0 + rt * 16 + q * 4 + i;
        if (row < n) out[(size_t)row * C + col] = acc[rt][ct][i] + bs;
      }
    }
  }
}

extern "C" void kernel_launch(void* const* d_in, const int* in_sizes, int n_in,
                              void* d_out, int out_size, void* d_ws, size_t ws_size,
                              hipStream_t stream) {
  const float* nodes = (const float*)d_in[0];
  const float* edges = (const float*)d_in[1];
  const int* senders = (const int*)d_in[2];
  const int* receivers = (const int*)d_in[3];
  const float* W = (const float*)d_in[4];
  const float* b_dense = (const float*)d_in[5];
  const float* bias = (const float*)d_in[6];
  float* out = (float*)d_out;
  int n = in_sizes[0] / C;
  int ne = in_sizes[1];
  int NB = (ne + EPB - 1) / EPB;          // phase-1 blocks
  int NBUCK = (n + 255) >> 8;             // coarse buckets (sender>>8)
  int M = 256 * NB;                       // scan table length
  int nb2 = (M + 1023) / 1024;

  char* ws = (char*)d_ws;
  size_t off = 0;
  auto alloc = [&](size_t b) { size_t r = off; off += (b + 255) & ~(size_t)255; return r; };
  float* degf = (float*)(ws + alloc((size_t)n * 4));
  int* offsets = (int*)(ws + alloc((size_t)(n + 1) * 4));
  int* hist = (int*)(ws + alloc((size_t)M * 4));
  int* bsums = (int*)(ws + alloc((size_t)nb2 * 4));
  int2* bkt = (int2*)(ws + alloc((size_t)ne * 8));
  int2* csr_wr = (int2*)(ws + alloc((size_t)ne * 8));
  unsigned* umax = (unsigned*)(ws + alloc(8));  // [0]=umax, [1]=ticket
  float* scalep = (float*)(ws + alloc(4));
  float* bsum = (float*)(ws + alloc(C * 4));
  short* Xb = (short*)(ws + alloc((size_t)n * KD * 2));
  short* Wt = (short*)(ws + alloc((size_t)KD * C * 2));
  (void)ws_size; (void)n_in; (void)out_size;

  hipMemsetAsync(umax, 0, 8, stream);  // zero umax + ticket

  // one fused prep launch: Wt transpose + bias-sum + nodes->bf16 slot0
  int prep_n = max(KD * C, n * 32);
  prep_kernel<<<(prep_n + 255) / 256, 256, 0, stream>>>(W, b_dense, bias, Wt, bsum, nodes, Xb, n);

  // CSR build — no global atomics (LDS atomics + scans only)
  p1_count_kernel<<<NB, 256, 0, stream>>>(senders, edges, ne, hist, NB, umax);
  scan1_kernel<<<nb2, 1024, 0, stream>>>(hist, hist, bsums, M);
  scan2_kernel<<<1, 1024, 0, stream>>>(bsums, nb2);
  p1_scatter_kernel<<<NB, 256, 0, stream>>>(senders, receivers, edges, ne, hist, bsums, NB, bkt);
  p2_finalize_kernel<<<NBUCK, 256, 0, stream>>>(bkt, hist, bsums, NB, NBUCK, ne, n, csr_wr,
                                                offsets, degf, umax, (int*)(umax + 1), scalep);

  int mvblocks = (n * 64 + 255) / 256;

  // Chebyshev recurrence, all state bf16 in Xb slots:
  matvec_kernel<<<mvblocks, 256, 0, stream>>>(Xb + 0 * C, nullptr, Xb + 1 * C,
                                              degf, offsets, csr_wr, scalep, 1.0f, n);
  matvec_kernel<<<mvblocks, 256, 0, stream>>>(Xb + 1 * C, Xb + 0 * C, Xb + 2 * C,
                                              degf, offsets, csr_wr, scalep, 2.0f, n);
  matvec_kernel<<<mvblocks, 256, 0, stream>>>(Xb + 2 * C, Xb + 1 * C, Xb + 3 * C,
                                              degf, offsets, csr_wr, scalep, 2.0f, n);
  matvec_kernel<<<mvblocks, 256, 0, stream>>>(Xb + 3 * C, Xb + 2 * C, Xb + 4 * C,
                                              degf, offsets, csr_wr, scalep, 2.0f, n);
  matvec_kernel<<<mvblocks, 256, 0, stream>>>(Xb + 4 * C, Xb + 3 * C, Xb + 5 * C,
                                              degf, offsets, csr_wr, scalep, 2.0f, n);

  // out = Xb @ vstack(W) + (sum_k b_k + bias), LDS-staged MFMA GEMM
  mfma_gemm_kernel<<<(n + 63) / 64, 256, 0, stream>>>(Xb, Wt, bsum, out, n);
}